// Round 1
// 602.908 us; speedup vs baseline: 1.5153x; 1.5153x over previous
//
#include <hip/hip_runtime.h>
#include <hip/hip_bf16.h>
#include <stdint.h>

#define NINF -100000.0f

constexpr int Bn = 64, Tn = 512, Hn = 768, Nn = 25;

// ---------------- dtype detection ----------------
// flags[0] = 1 if float tensors are bf16, 0 if f32
// flags[1] = bool storage width in bytes (1/4/8)
// flags[2] = padding_index value
__global__ __launch_bounds__(64) void k_detect(const void* emb, const void* mask,
                                               const void* padidx, int* flags) {
    int lane = threadIdx.x;
    const uint16_t* e16 = (const uint16_t*)emb;
    uint16_t v = e16[lane];
    int ex = (v >> 7) & 0xFF;
    bool sane = (ex >= 100 && ex <= 140);
    unsigned long long ball = __ballot(sane);
    int cnt = __popcll(ball);
    if (lane == 0) {
        flags[0] = (cnt >= 56) ? 1 : 0;
        const int* mw = (const int*)mask;
        int w0 = mw[0];
        int w1 = mw[1];
        int bw;
        if ((unsigned)w0 > 1u) bw = 1;
        else if (w0 == 1 && w1 == 0) bw = 8;
        else bw = 4;
        flags[1] = bw;
        flags[2] = ((const int*)padidx)[0];
    }
}

__device__ inline float ldf(const void* p, int i, bool isbf) {
    if (isbf) return __bfloat162float(((const __hip_bfloat16*)p)[i]);
    return ((const float*)p)[i];
}
__device__ inline int ldb(const void* p, int i, int bw) {
    if (bw == 1) return (int)((const uint8_t*)p)[i];
    if (bw == 8) return ((const int*)p)[2 * i];
    return ((const int*)p)[i];
}

// ---------------- convert constants to canonical f32 forms in ws ----------------
__global__ __launch_bounds__(256) void k_convert(
    const void* W, const void* bv, const void* trans, const void* startt, const void* endt,
    const void* mask, const void* sc, const void* ec, const void* tc,
    const int* flags, float* wsWf,
    float* wsb, float* wsstart, float* wsend, float* wsscm, float* wsecm,
    float* wstrans, float* wstc, int* lengths)
{
    bool isbf = flags[0] != 0;
    int bw = flags[1];
    int gid = blockIdx.x * blockDim.x + threadIdx.x;
    int gsz = gridDim.x * blockDim.x;
    for (int i = gid; i < Hn * Nn; i += gsz) wsWf[i] = ldf(W, i, isbf);
    for (int i = gid; i < Nn; i += gsz) {
        wsb[i]     = ldf(bv, i, isbf);
        wsstart[i] = ldf(startt, i, isbf);
        wsend[i]   = ldf(endt, i, isbf);
        wsscm[i]   = ldb(sc, i, bw) ? 0.0f : NINF;
        wsecm[i]   = ldb(ec, i, bw) ? 0.0f : NINF;
    }
    for (int i = gid; i < Nn * Nn; i += gsz) {
        wstrans[i] = ldf(trans, i, isbf);
        wstc[i]    = ldb(tc, i, bw) ? 0.0f : NINF;
    }
    for (int r = gid; r < Bn; r += gsz) {
        int s = 0;
        for (int t = 0; t < Tn; t++) s += (ldb(mask, r * Tn + t, bw) ? 1 : 0);
        lengths[r] = s;
    }
}

// ---------------- logits: strict np.einsum replication ----------------
// 2 threads per row: half0 owns j=0..11, half1 owns j=12..24 (both float4-aligned
// into the 32-float-padded wtile rows). Per-j accumulation remains sequential f32
// (mul, add) over h = 0..767 ascending, NO fma — bit-identical to the reference
// einsum association. 256 blocks x 256 threads = 1024 waves (all 4 SIMDs/CU busy).
__global__ __launch_bounds__(256) void k_gemm(
    const void* embv, const float* wsWf, const float* wsb, const float* wstrans,
    const float* wsstart, const float* wsend,
    const int* lengths, const int* flags,
    float* logitsF, void* out)
{
    __shared__ float etile[128][65];   // 128 rows x 64-h chunk, padded (odd stride)
    __shared__ float wtile[64][32];    // 64-h chunk x 25 cols, padded to 32 for float4
    __shared__ float lgs[128][26];
    __shared__ float s_trans[625];
    __shared__ float s_start[25], s_end[25], s_b[25];

    int tid  = threadIdx.x;            // 0..255
    int r    = tid >> 1;               // row within block: 0..127
    int half = tid & 1;
    int j0   = half ? 12 : 0;          // half0: j 0..11, half1: j 12..24
    int row0 = blockIdx.x * 128;
    int row  = row0 + r;
    bool isbf = flags[0] != 0;

    for (int i = tid; i < 625; i += 256) s_trans[i] = wstrans[i];
    if (tid < 25) { s_start[tid] = wsstart[tid]; s_end[tid] = wsend[tid]; s_b[tid] = wsb[tid]; }

    float acc[13];
#pragma unroll
    for (int k = 0; k < 13; k++) acc[k] = 0.0f;

    for (int c = 0; c < 12; c++) {
        __syncthreads();
        // stage 128 rows x 64 h — vectorized 8B/16B loads, coalesced
        if (isbf) {
            const uint16_t* ep = (const uint16_t*)embv;
#pragma unroll
            for (int it = 0; it < 8; it++) {
                int idx = it * 256 + tid;        // 0..2047
                int rr = idx >> 4;
                int q  = idx & 15;
                const ushort4* p4 = (const ushort4*)(ep + (size_t)(row0 + rr) * Hn + c * 64);
                ushort4 u = p4[q];
                etile[rr][q * 4 + 0] = __bfloat162float(*(const __hip_bfloat16*)&u.x);
                etile[rr][q * 4 + 1] = __bfloat162float(*(const __hip_bfloat16*)&u.y);
                etile[rr][q * 4 + 2] = __bfloat162float(*(const __hip_bfloat16*)&u.z);
                etile[rr][q * 4 + 3] = __bfloat162float(*(const __hip_bfloat16*)&u.w);
            }
        } else {
            const float* ep = (const float*)embv;
#pragma unroll
            for (int it = 0; it < 8; it++) {
                int idx = it * 256 + tid;
                int rr = idx >> 4;
                int q  = idx & 15;
                const float4* p4 = (const float4*)(ep + (size_t)(row0 + rr) * Hn + c * 64);
                float4 v = p4[q];
                etile[rr][q * 4 + 0] = v.x;
                etile[rr][q * 4 + 1] = v.y;
                etile[rr][q * 4 + 2] = v.z;
                etile[rr][q * 4 + 3] = v.w;
            }
        }
        // stage W chunk
        for (int i = tid; i < 1600; i += 256) {
            int hh = i / 25, j = i - hh * 25;
            wtile[hh][j] = wsWf[(size_t)(c * 64 + hh) * 25 + j];
        }
        __syncthreads();
        {
#pragma clang fp contract(off)
#pragma unroll 4
            for (int hh = 0; hh < 64; hh++) {
                float e = etile[r][hh];
                const float4* wp = (const float4*)&wtile[hh][j0];  // 0B or 48B: 16B aligned
                float4 w0 = wp[0];
                float4 w1 = wp[1];
                float4 w2 = wp[2];
                float  wl = wtile[hh][j0 + 12];
                acc[0]  = acc[0]  + e * w0.x;
                acc[1]  = acc[1]  + e * w0.y;
                acc[2]  = acc[2]  + e * w0.z;
                acc[3]  = acc[3]  + e * w0.w;
                acc[4]  = acc[4]  + e * w1.x;
                acc[5]  = acc[5]  + e * w1.y;
                acc[6]  = acc[6]  + e * w1.z;
                acc[7]  = acc[7]  + e * w1.w;
                acc[8]  = acc[8]  + e * w2.x;
                acc[9]  = acc[9]  + e * w2.y;
                acc[10] = acc[10] + e * w2.z;
                acc[11] = acc[11] + e * w2.w;
                acc[12] = acc[12] + e * wl;     // half0's acc[12] (=j12) unused at write
            }
        }
    }

    // logits = einsum + b  (one f32 add, ref association); halves write disjoint j
    int nj = half ? 13 : 12;
    {
#pragma clang fp contract(off)
        for (int k = 0; k < nj; k++) {
            int j = j0 + k;
            float lg = acc[k] + s_b[j];
            lgs[r][j] = lg;
            logitsF[(size_t)row * 25 + j] = lg;
        }
    }
    __syncthreads();

    // lp epilogue
    int bidx = row0 >> 9;
    int len  = lengths[bidx];
    int last = len - 1;
    for (int rr = 0; rr < 128; rr++) {
        int rw = row0 + rr;
        int t = rw & 511;
        bool isfirst = (t == 0);
        bool islast  = (t == last);
        {
#pragma clang fp contract(off)
            for (int e = tid; e < 625; e += 256) {
                int i = e / 25;
                int j = e - i * 25;
                float lg = lgs[rr][j];
                float v;
                if (isfirst) v = s_start[j] + lg;
                else         v = lg + s_trans[e];
                if (islast)  v += s_end[j];
                size_t o = (size_t)rw * 625 + e;
                if (isbf) ((__hip_bfloat16*)out)[o] = __float2bfloat16(v);
                else      ((float*)out)[o] = v;
            }
        }
    }
}

// ---------------- Viterbi: 1 wave per batch, exact f32 replication ----------------
// 2-way old-state split: lanes 0..24 (half A) reduce i=0..12, lanes 32..56 (half B)
// reduce i=13..24; one shfl_xor(32) pair combines with strict-> "B beats A", which
// is exactly jnp.argmax first-max semantics (half A holds the lower indices).
// Alpha gathers use ds_bpermute (batched at step top, latency hidden under the
// independent v computation). logitsF is read with a distance-2 register prefetch —
// no LDS staging, no per-chunk barriers.
__global__ __launch_bounds__(64) void k_viterbi(
    const float* logitsF, const float* wstrans, const float* wstc,
    const float* wsstart, const float* wsend, const float* wsscm, const float* wsecm,
    const int* lengths, const int* flags, void* out)
{
    __shared__ float   aT[32];
    __shared__ uint8_t bp[511][32];
    __shared__ uint8_t tags[512];

    int b  = blockIdx.x;
    int L  = threadIdx.x;
    int jl = L & 31;
    int ihalf = L >> 5;
    bool act = (jl < 25);
    int j  = act ? jl : 0;
    int i0 = ihalf ? 13 : 0;
    int NI = ihalf ? 12 : 13;      // real candidates in this half
    int len  = lengths[b];
    int last = len - 1;
    bool isbf = flags[0] != 0;
    int padv = flags[2];

    // Per-lane constants. ttc = trr + tcc is exact when tcc==0 (the only case whose
    // candidates can ever win on a followed path; tc|eye guarantees the self-loop,
    // so NINF-class candidates lose by >=9e4 and their reassociation is unobservable).
    float trr[13], tcc[13], ttc[13], veq[13];
#pragma unroll
    for (int k = 0; k < 13; k++) {
        int i = i0 + k;
        if (k >= NI) {             // pad slot (half B k=12): ai reads lane 25 (-3e38), never wins
            trr[k] = 0.0f; tcc[k] = 0.0f; ttc[k] = 0.0f; veq[k] = 0.0f;
        } else {
            float tr = wstrans[i * 25 + j];
            float tv = wstc[i * 25 + j];
            trr[k] = tr;
            tcc[k] = tv;
            ttc[k] = tr + tv;
            veq[k] = (i == j) ? 0.0f : NINF;
        }
    }
    float endj = wsend[j];
    float ecmj = wsecm[j];
    const float* lgb = logitsF + (size_t)b * (Tn * Nn);

    // alpha0[j] = (start[j] + logits[b,0,j]) + scm[j]
    float areg;
    {
#pragma clang fp contract(off)
        areg = act ? ((wsstart[j] + lgb[j]) + wsscm[j]) : -3.0e38f;
    }

    float Lg0 = lgb[1 * 25 + j];   // logits row for t=1
    float Lg1 = lgb[2 * 25 + j];   // t=2
    int baddr = i0 * 4;

    for (int t = 1; t < 512; ++t) {
        float Lgn = Lg1;
        if (t + 2 < 512) Lgn = lgb[(t + 2) * 25 + j];   // distance-2 prefetch

        float ai[13];
#pragma unroll
        for (int k = 0; k < 13; k++)
            ai[k] = __int_as_float(__builtin_amdgcn_ds_bpermute(baddr + 4 * k, __float_as_int(areg)));

        float m; int mi;
        if (t >= len) {
            m = ai[0] + veq[0]; mi = i0;
#pragma unroll
            for (int k = 1; k < 13; k++) {
                float sc = ai[k] + veq[k];
                if (sc > m) { m = sc; mi = i0 + k; }
            }
        } else if (t == last) {
#pragma clang fp contract(off)
            float v0 = (((Lg0 + trr[0]) + endj) + tcc[0]) + ecmj;
            m = ai[0] + v0; mi = i0;
#pragma unroll
            for (int k = 1; k < 13; k++) {
                float v = (((Lg0 + trr[k]) + endj) + tcc[k]) + ecmj;
                float sc = ai[k] + v;
                if (sc > m) { m = sc; mi = i0 + k; }
            }
        } else {
#pragma clang fp contract(off)
            float v0 = Lg0 + ttc[0];
            m = ai[0] + v0; mi = i0;
#pragma unroll
            for (int k = 1; k < 13; k++) {
                float v = Lg0 + ttc[k];
                float sc = ai[k] + v;
                if (sc > m) { m = sc; mi = i0 + k; }
            }
        }

        // combine halves: A = i 0..12 (lower indices), B = i 13..24; B wins only if strictly greater
        float mo  = __shfl_xor(m, 32, 64);
        int   mio = __shfl_xor(mi, 32, 64);
        float vA = ihalf ? mo  : m;
        int   iA = ihalf ? mio : mi;
        float vB = ihalf ? m   : mo;
        int   iB = ihalf ? mi  : mio;
        bool tB = (vB > vA);
        float Mv = tB ? vB : vA;
        int   Mi = tB ? iB : iA;
        areg = act ? Mv : -3.0e38f;
        if (L < 25) bp[t - 1][L] = (uint8_t)Mi;
        Lg0 = Lg1; Lg1 = Lgn;
    }

    if (L < 25) aT[L] = areg;
    __syncthreads();
    if (L == 0) {
        float m2 = aT[0];
        int mi2 = 0;
        for (int jx = 1; jx < 25; jx++) {
            if (aT[jx] > m2) { m2 = aT[jx]; mi2 = jx; }
        }
        int tag = mi2;
        tags[511] = (uint8_t)tag;
        for (int k2 = 510; k2 >= 0; k2--) {
            tag = bp[k2][tag];
            tags[k2] = (uint8_t)tag;
        }
    }
    __syncthreads();

    size_t base = 20480000ull;  // B*T*N*N
    for (int t = L; t < 512; t += 64) {
        float val = (t < len) ? (float)tags[t] : (float)padv;
        size_t o = base + (size_t)b * 512 + t;
        if (isbf) ((__hip_bfloat16*)out)[o] = __float2bfloat16(val);
        else      ((float*)out)[o] = val;
    }
}

extern "C" void kernel_launch(void* const* d_in, const int* in_sizes, int n_in,
                              void* d_out, int out_size, void* d_ws, size_t ws_size,
                              hipStream_t stream) {
    const void* emb  = d_in[0];
    const void* W    = d_in[1];
    const void* bv   = d_in[2];
    const void* tr   = d_in[3];
    const void* st   = d_in[4];
    const void* en   = d_in[5];
    const void* mask = d_in[6];
    const void* sc   = d_in[7];
    const void* ec   = d_in[8];
    const void* tc   = d_in[9];
    const void* pad  = d_in[10];

    char* ws = (char*)d_ws;
    int*    flags    = (int*)ws;             // 64 B
    int*    lengths  = (int*)(ws + 64);      // 256 B
    float*  wsb      = (float*)(ws + 384);
    float*  wsstart  = (float*)(ws + 512);
    float*  wsend    = (float*)(ws + 640);
    float*  wsscm    = (float*)(ws + 768);
    float*  wsecm    = (float*)(ws + 896);
    float*  wstrans  = (float*)(ws + 1024);  // 2500 B
    float*  wstc     = (float*)(ws + 3584);  // 2500 B
    float*  wsWf     = (float*)(ws + 6144);  // 76800 B -> ends 82944
    float*  logitsF  = (float*)(ws + 82944); // 3276800 B -> ends ~3.36 MB

    k_detect<<<1, 64, 0, stream>>>(emb, mask, pad, flags);
    k_convert<<<64, 256, 0, stream>>>(W, bv, tr, st, en, mask, sc, ec, tc, flags,
                                      wsWf, wsb, wsstart, wsend, wsscm, wsecm,
                                      wstrans, wstc, lengths);
    k_gemm<<<256, 256, 0, stream>>>(emb, wsWf, wsb, wstrans, wsstart, wsend,
                                    lengths, flags, logitsF, d_out);
    k_viterbi<<<64, 64, 0, stream>>>(logitsF, wstrans, wstc, wsstart, wsend,
                                     wsscm, wsecm, lengths, flags, d_out);
}

// Round 3
// 568.566 us; speedup vs baseline: 1.6068x; 1.0604x over previous
//
#include <hip/hip_runtime.h>
#include <hip/hip_bf16.h>
#include <stdint.h>

#define NINF -100000.0f

constexpr int Bn = 64, Tn = 512, Hn = 768, Nn = 25;

typedef int int2v __attribute__((ext_vector_type(2)));

// ---------------- dtype detection ----------------
// flags[0] = 1 if float tensors are bf16, 0 if f32
// flags[1] = bool storage width in bytes (1/4/8)
// flags[2] = padding_index value
__global__ __launch_bounds__(64) void k_detect(const void* emb, const void* mask,
                                               const void* padidx, int* flags) {
    int lane = threadIdx.x;
    const uint16_t* e16 = (const uint16_t*)emb;
    uint16_t v = e16[lane];
    int ex = (v >> 7) & 0xFF;
    bool sane = (ex >= 100 && ex <= 140);
    unsigned long long ball = __ballot(sane);
    int cnt = __popcll(ball);
    if (lane == 0) {
        flags[0] = (cnt >= 56) ? 1 : 0;
        const int* mw = (const int*)mask;
        int w0 = mw[0];
        int w1 = mw[1];
        int bw;
        if ((unsigned)w0 > 1u) bw = 1;
        else if (w0 == 1 && w1 == 0) bw = 8;
        else bw = 4;
        flags[1] = bw;
        flags[2] = ((const int*)padidx)[0];
    }
}

__device__ inline float ldf(const void* p, int i, bool isbf) {
    if (isbf) return __bfloat162float(((const __hip_bfloat16*)p)[i]);
    return ((const float*)p)[i];
}
__device__ inline int ldb(const void* p, int i, int bw) {
    if (bw == 1) return (int)((const uint8_t*)p)[i];
    if (bw == 8) return ((const int*)p)[2 * i];
    return ((const int*)p)[i];
}

// ---------------- convert constants to canonical f32 forms in ws ----------------
__global__ __launch_bounds__(256) void k_convert(
    const void* W, const void* bv, const void* trans, const void* startt, const void* endt,
    const void* mask, const void* sc, const void* ec, const void* tc,
    const int* flags, float* wsWf,
    float* wsb, float* wsstart, float* wsend, float* wsscm, float* wsecm,
    float* wstrans, float* wstc, int* lengths)
{
    bool isbf = flags[0] != 0;
    int bw = flags[1];
    int gid = blockIdx.x * blockDim.x + threadIdx.x;
    int gsz = gridDim.x * blockDim.x;
    for (int i = gid; i < Hn * Nn; i += gsz) wsWf[i] = ldf(W, i, isbf);
    for (int i = gid; i < Nn; i += gsz) {
        wsb[i]     = ldf(bv, i, isbf);
        wsstart[i] = ldf(startt, i, isbf);
        wsend[i]   = ldf(endt, i, isbf);
        wsscm[i]   = ldb(sc, i, bw) ? 0.0f : NINF;
        wsecm[i]   = ldb(ec, i, bw) ? 0.0f : NINF;
    }
    for (int i = gid; i < Nn * Nn; i += gsz) {
        wstrans[i] = ldf(trans, i, isbf);
        wstc[i]    = ldb(tc, i, bw) ? 0.0f : NINF;
    }
    for (int r = gid; r < Bn; r += gsz) {
        int s = 0;
        for (int t = 0; t < Tn; t++) s += (ldb(mask, r * Tn + t, bw) ? 1 : 0);
        lengths[r] = s;
    }
}

// ---------------- logits: strict np.einsum replication ----------------
// 2 threads per row: half0 owns j=0..11, half1 owns j=12..24. Per-j accumulation is
// sequential f32 (mul, add) over h = 0..767 ascending, NO fma — bit-identical to the
// reference einsum association. Epilogue (lp expansion) moved to k_lp.
__global__ __launch_bounds__(256) void k_gemm(
    const void* embv, const float* wsWf, const float* wsb,
    const int* flags, float* logitsF)
{
    __shared__ float etile[128][65];   // 128 rows x 64-h chunk, padded (odd stride)
    __shared__ float wtile[64][32];    // 64-h chunk x 25 cols, padded to 32 for float4
    __shared__ float s_b[25];

    int tid  = threadIdx.x;            // 0..255
    int r    = tid >> 1;               // row within block: 0..127
    int half = tid & 1;
    int j0   = half ? 12 : 0;          // half0: j 0..11, half1: j 12..24
    int row0 = blockIdx.x * 128;
    int row  = row0 + r;
    bool isbf = flags[0] != 0;

    if (tid < 25) s_b[tid] = wsb[tid];

    float acc[13];
#pragma unroll
    for (int k = 0; k < 13; k++) acc[k] = 0.0f;

    for (int c = 0; c < 12; c++) {
        __syncthreads();
        // stage 128 rows x 64 h — vectorized 8B/16B loads, coalesced
        if (isbf) {
            const uint16_t* ep = (const uint16_t*)embv;
#pragma unroll
            for (int it = 0; it < 8; it++) {
                int idx = it * 256 + tid;        // 0..2047
                int rr = idx >> 4;
                int q  = idx & 15;
                const ushort4* p4 = (const ushort4*)(ep + (size_t)(row0 + rr) * Hn + c * 64);
                ushort4 u = p4[q];
                etile[rr][q * 4 + 0] = __bfloat162float(*(const __hip_bfloat16*)&u.x);
                etile[rr][q * 4 + 1] = __bfloat162float(*(const __hip_bfloat16*)&u.y);
                etile[rr][q * 4 + 2] = __bfloat162float(*(const __hip_bfloat16*)&u.z);
                etile[rr][q * 4 + 3] = __bfloat162float(*(const __hip_bfloat16*)&u.w);
            }
        } else {
            const float* ep = (const float*)embv;
#pragma unroll
            for (int it = 0; it < 8; it++) {
                int idx = it * 256 + tid;
                int rr = idx >> 4;
                int q  = idx & 15;
                const float4* p4 = (const float4*)(ep + (size_t)(row0 + rr) * Hn + c * 64);
                float4 v = p4[q];
                etile[rr][q * 4 + 0] = v.x;
                etile[rr][q * 4 + 1] = v.y;
                etile[rr][q * 4 + 2] = v.z;
                etile[rr][q * 4 + 3] = v.w;
            }
        }
        // stage W chunk
        for (int i = tid; i < 1600; i += 256) {
            int hh = i / 25, j = i - hh * 25;
            wtile[hh][j] = wsWf[(size_t)(c * 64 + hh) * 25 + j];
        }
        __syncthreads();
        {
#pragma clang fp contract(off)
#pragma unroll 4
            for (int hh = 0; hh < 64; hh++) {
                float e = etile[r][hh];
                const float4* wp = (const float4*)&wtile[hh][j0];  // 0B or 48B: 16B aligned
                float4 w0 = wp[0];
                float4 w1 = wp[1];
                float4 w2 = wp[2];
                float  wl = wtile[hh][j0 + 12];
                acc[0]  = acc[0]  + e * w0.x;
                acc[1]  = acc[1]  + e * w0.y;
                acc[2]  = acc[2]  + e * w0.z;
                acc[3]  = acc[3]  + e * w0.w;
                acc[4]  = acc[4]  + e * w1.x;
                acc[5]  = acc[5]  + e * w1.y;
                acc[6]  = acc[6]  + e * w1.z;
                acc[7]  = acc[7]  + e * w1.w;
                acc[8]  = acc[8]  + e * w2.x;
                acc[9]  = acc[9]  + e * w2.y;
                acc[10] = acc[10] + e * w2.z;
                acc[11] = acc[11] + e * w2.w;
                acc[12] = acc[12] + e * wl;     // half0's acc[12] (=j12) unused at write
            }
        }
    }

    // logits = einsum + b  (one f32 add, ref association); halves write disjoint j
    int nj = half ? 13 : 12;
    {
#pragma clang fp contract(off)
        for (int k = 0; k < nj; k++) {
            int j = j0 + k;
            float lg = acc[k] + s_b[j];
            logitsF[(size_t)row * 25 + j] = lg;
        }
    }
}

// ---------------- lp expansion: fully parallel epilogue ----------------
// out[rw, i, j] = t==0 ? start[j]+lg : lg+trans[i][j]; +end[j] at t==last.
// Identical f32 add ordering to the reference; reads logitsF (bit-exact f32).
__global__ __launch_bounds__(256) void k_lp(
    const float* logitsF, const float* wstrans, const float* wsstart, const float* wsend,
    const int* lengths, const int* flags, void* out)
{
    __shared__ float s_trans[625];
    __shared__ float s_start[25], s_end[25];
    int tid = threadIdx.x;
    for (int i = tid; i < 625; i += 256) s_trans[i] = wstrans[i];
    if (tid < 25) { s_start[tid] = wsstart[tid]; s_end[tid] = wsend[tid]; }
    __syncthreads();

    bool isbf = flags[0] != 0;
    int rw0 = blockIdx.x * 16;           // 2048 blocks; 16 (b,t) rows each, same batch
    int b = rw0 >> 9;
    int last = lengths[b] - 1;
    const float* lg0 = logitsF + (size_t)rw0 * 25;
    size_t obase = (size_t)rw0 * 625;

    for (int idx = tid; idx < 16 * 625; idx += 256) {
        int rr = idx / 625;
        int e  = idx - rr * 625;
        int i  = e / 25;
        int j  = e - i * 25;
        int t  = (rw0 + rr) & 511;
        float lg = lg0[rr * 25 + j];
        float v;
        {
#pragma clang fp contract(off)
            if (t == 0) v = s_start[j] + lg;
            else        v = lg + s_trans[e];
            if (t == last) v += s_end[j];
        }
        size_t o = obase + idx;
        if (isbf) ((__hip_bfloat16*)out)[o] = __float2bfloat16(v);
        else      ((float*)out)[o] = v;
    }
}

// ---------------- Viterbi: 1 wave per batch, exact f32 replication ----------------
// 2-way old-state split: lanes 0..24 (half A) reduce i=0..12, lanes 32..56 (half B)
// reduce i=13..24. Per-half reduction is a depth-4 TREE (padded to 16 with -3e38
// sentinels); pairwise combine keeps the LEFT (lower-index) element unless the right
// is strictly greater — associative and bit-identical to first-occurrence argmax.
// Cross-half combine: v_permlane32_swap with a=b=x returns, at EVERY lane, the
// multiset {own value, lane±32 value} across its two result words (true for either
// row-swap direction). Value and index go through identical permlanes, so the two
// (value,index) pairs are exactly {half-A result, half-B result} in some order;
// first-max with index tie-break (A's index < 13 <= B's index) reproduces
// jnp.argmax first-occurrence semantics order-independently.
__global__ __launch_bounds__(64) void k_viterbi(
    const float* logitsF, const float* wstrans, const float* wstc,
    const float* wsstart, const float* wsend, const float* wsscm, const float* wsecm,
    const int* lengths, const int* flags, void* out)
{
    __shared__ float   aT[32];
    __shared__ uint8_t bp[511][32];
    __shared__ uint8_t tags[512];

    int b  = blockIdx.x;
    int L  = threadIdx.x;
    int jl = L & 31;
    int ihalf = L >> 5;
    bool act = (jl < 25);
    int j  = act ? jl : 0;
    int i0 = ihalf ? 13 : 0;
    int NI = ihalf ? 12 : 13;      // real candidates in this half
    int len  = lengths[b];
    int last = len - 1;
    bool isbf = flags[0] != 0;
    int padv = flags[2];

    const float PADV = -3.0e38f;

    // Loop-carried per-lane constants. ttc = trans + tc pre-add is exact when tc==0
    // (the only candidates that can win on a followed path; tc|eye guarantees the
    // self-loop, so NINF-class candidates lose by >=9e4). trr/tcc for the single
    // t==last step are reloaded inside that (once-per-block) branch.
    float ttc[13], veq[13];
#pragma unroll
    for (int k = 0; k < 13; k++) {
        int i = i0 + k;
        if (k >= NI) {             // pad slot (half B k=12): ai reads lane 25 (-3e38), never wins
            ttc[k] = 0.0f; veq[k] = 0.0f;
        } else {
            ttc[k] = wstrans[i * 25 + j] + wstc[i * 25 + j];
            veq[k] = (i == j) ? 0.0f : NINF;
        }
    }
    float endj = wsend[j];
    float ecmj = wsecm[j];
    const float* lgb = logitsF + (size_t)b * (Tn * Nn);

    // alpha0[j] = (start[j] + logits[b,0,j]) + scm[j]
    float areg;
    {
#pragma clang fp contract(off)
        areg = act ? ((wsstart[j] + lgb[j]) + wsscm[j]) : PADV;
    }

    float Lg0 = lgb[1 * 25 + j];   // logits row for t=1
    float Lg1 = lgb[2 * 25 + j];   // t=2
    int baddr = i0 * 4;

    for (int t = 1; t < 512; ++t) {
        float Lgn = Lg1;
        if (t + 2 < 512) Lgn = lgb[(t + 2) * 25 + j];   // distance-2 prefetch

        float ai[13];
#pragma unroll
        for (int k = 0; k < 13; k++)
            ai[k] = __int_as_float(__builtin_amdgcn_ds_bpermute(baddr + 4 * k, __float_as_int(areg)));

        float s[16];
        if (t >= len) {
#pragma unroll
            for (int k = 0; k < 13; k++) s[k] = ai[k] + veq[k];
        } else if (t == last) {
#pragma clang fp contract(off)
#pragma unroll
            for (int k = 0; k < 13; k++) {
                int ii = (i0 + k > 24) ? 24 : (i0 + k);   // clamp pad slot (never wins)
                float tr = wstrans[ii * 25 + j];
                float tv = wstc[ii * 25 + j];
                float v = (((Lg0 + tr) + endj) + tv) + ecmj;
                s[k] = ai[k] + v;
            }
        } else {
#pragma clang fp contract(off)
#pragma unroll
            for (int k = 0; k < 13; k++) {
                float v = Lg0 + ttc[k];
                s[k] = ai[k] + v;
            }
        }
        s[13] = PADV; s[14] = PADV; s[15] = PADV;

        // depth-4 tree argmax, first-max (lower local index wins ties)
        float m1[8]; int i1[8];
#pragma unroll
        for (int p = 0; p < 8; p++) {
            bool g = s[2 * p + 1] > s[2 * p];
            m1[p] = g ? s[2 * p + 1] : s[2 * p];
            i1[p] = g ? (2 * p + 1) : (2 * p);
        }
        float m2[4]; int i2[4];
#pragma unroll
        for (int p = 0; p < 4; p++) {
            bool g = m1[2 * p + 1] > m1[2 * p];
            m2[p] = g ? m1[2 * p + 1] : m1[2 * p];
            i2[p] = g ? i1[2 * p + 1] : i1[2 * p];
        }
        float m3[2]; int i3[2];
#pragma unroll
        for (int p = 0; p < 2; p++) {
            bool g = m2[2 * p + 1] > m2[2 * p];
            m3[p] = g ? m2[2 * p + 1] : m2[2 * p];
            i3[p] = g ? i2[2 * p + 1] : i2[2 * p];
        }
        bool g4 = m3[1] > m3[0];
        float m = g4 ? m3[1] : m3[0];
        int  mi = i0 + (g4 ? i3[1] : i3[0]);

        // cross-half combine via v_permlane32_swap (VALU, no DS round-trip).
        // {(c0,j0c),(c1,j1c)} == {(mA,iA),(mB,iB)} in unknown order at every lane;
        // pick higher value, tie -> lower index == first-occurrence argmax.
        int2v pv = __builtin_amdgcn_permlane32_swap(__float_as_int(m), __float_as_int(m), false, false);
        int2v pi = __builtin_amdgcn_permlane32_swap(mi, mi, false, false);
        float c0 = __int_as_float(pv[0]); int j0c = pi[0];
        float c1 = __int_as_float(pv[1]); int j1c = pi[1];
        bool take1 = (c1 > c0) || ((c1 == c0) && (j1c < j0c));
        float Mv = take1 ? c1 : c0;
        int   Mi = take1 ? j1c : j0c;
        areg = act ? Mv : PADV;             // lanes 25..31 stay PADV (bpermute pad source)
        if (L < 25) bp[t - 1][L] = (uint8_t)Mi;
        Lg0 = Lg1; Lg1 = Lgn;
    }

    if (L < 25) aT[L] = areg;
    __syncthreads();
    if (L == 0) {
        float m2 = aT[0];
        int mi2 = 0;
        for (int jx = 1; jx < 25; jx++) {
            if (aT[jx] > m2) { m2 = aT[jx]; mi2 = jx; }
        }
        int tag = mi2;
        tags[511] = (uint8_t)tag;
        for (int k2 = 510; k2 >= 0; k2--) {
            tag = bp[k2][tag];
            tags[k2] = (uint8_t)tag;
        }
    }
    __syncthreads();

    size_t base = 20480000ull;  // B*T*N*N
    for (int t = L; t < 512; t += 64) {
        float val = (t < len) ? (float)tags[t] : (float)padv;
        size_t o = base + (size_t)b * 512 + t;
        if (isbf) ((__hip_bfloat16*)out)[o] = __float2bfloat16(val);
        else      ((float*)out)[o] = val;
    }
}

extern "C" void kernel_launch(void* const* d_in, const int* in_sizes, int n_in,
                              void* d_out, int out_size, void* d_ws, size_t ws_size,
                              hipStream_t stream) {
    const void* emb  = d_in[0];
    const void* W    = d_in[1];
    const void* bv   = d_in[2];
    const void* tr   = d_in[3];
    const void* st   = d_in[4];
    const void* en   = d_in[5];
    const void* mask = d_in[6];
    const void* sc   = d_in[7];
    const void* ec   = d_in[8];
    const void* tc   = d_in[9];
    const void* pad  = d_in[10];

    char* ws = (char*)d_ws;
    int*    flags    = (int*)ws;             // 64 B
    int*    lengths  = (int*)(ws + 64);      // 256 B
    float*  wsb      = (float*)(ws + 384);
    float*  wsstart  = (float*)(ws + 512);
    float*  wsend    = (float*)(ws + 640);
    float*  wsscm    = (float*)(ws + 768);
    float*  wsecm    = (float*)(ws + 896);
    float*  wstrans  = (float*)(ws + 1024);  // 2500 B
    float*  wstc     = (float*)(ws + 3584);  // 2500 B
    float*  wsWf     = (float*)(ws + 6144);  // 76800 B -> ends 82944
    float*  logitsF  = (float*)(ws + 82944); // 3276800 B -> ends ~3.36 MB

    k_detect<<<1, 64, 0, stream>>>(emb, mask, pad, flags);
    k_convert<<<64, 256, 0, stream>>>(W, bv, tr, st, en, mask, sc, ec, tc, flags,
                                      wsWf, wsb, wsstart, wsend, wsscm, wsecm,
                                      wstrans, wstc, lengths);
    k_gemm<<<256, 256, 0, stream>>>(emb, wsWf, wsb, flags, logitsF);
    k_viterbi<<<64, 64, 0, stream>>>(logitsF, wstrans, wstc, wsstart, wsend,
                                     wsscm, wsecm, lengths, flags, d_out);
    k_lp<<<2048, 256, 0, stream>>>(logitsF, wstrans, wsstart, wsend,
                                   lengths, flags, d_out);
}

// Round 4
// 495.012 us; speedup vs baseline: 1.8456x; 1.1486x over previous
//
#include <hip/hip_runtime.h>
#include <hip/hip_bf16.h>
#include <stdint.h>

#define NINF -100000.0f

constexpr int Bn = 64, Tn = 512, Hn = 768, Nn = 25;

// ---------------- dtype detection ----------------
// flags[0] = 1 if float tensors are bf16, 0 if f32
// flags[1] = bool storage width in bytes (1/4/8)
// flags[2] = padding_index value
__global__ __launch_bounds__(64) void k_detect(const void* emb, const void* mask,
                                               const void* padidx, int* flags) {
    int lane = threadIdx.x;
    const uint16_t* e16 = (const uint16_t*)emb;
    uint16_t v = e16[lane];
    int ex = (v >> 7) & 0xFF;
    bool sane = (ex >= 100 && ex <= 140);
    unsigned long long ball = __ballot(sane);
    int cnt = __popcll(ball);
    if (lane == 0) {
        flags[0] = (cnt >= 56) ? 1 : 0;
        const int* mw = (const int*)mask;
        int w0 = mw[0];
        int w1 = mw[1];
        int bw;
        if ((unsigned)w0 > 1u) bw = 1;
        else if (w0 == 1 && w1 == 0) bw = 8;
        else bw = 4;
        flags[1] = bw;
        flags[2] = ((const int*)padidx)[0];
    }
}

__device__ inline float ldf(const void* p, int i, bool isbf) {
    if (isbf) return __bfloat162float(((const __hip_bfloat16*)p)[i]);
    return ((const float*)p)[i];
}
__device__ inline int ldb(const void* p, int i, int bw) {
    if (bw == 1) return (int)((const uint8_t*)p)[i];
    if (bw == 8) return ((const int*)p)[2 * i];
    return ((const int*)p)[i];
}

// ---------------- convert constants to canonical f32 forms in ws ----------------
__global__ __launch_bounds__(256) void k_convert(
    const void* W, const void* bv, const void* trans, const void* startt, const void* endt,
    const void* sc, const void* ec, const void* tc,
    const int* flags, float* wsWf,
    float* wsb, float* wsstart, float* wsend, float* wsscm, float* wsecm,
    float* wstrans, float* wstc)
{
    bool isbf = flags[0] != 0;
    int bw = flags[1];
    int gid = blockIdx.x * blockDim.x + threadIdx.x;
    int gsz = gridDim.x * blockDim.x;
    for (int i = gid; i < Hn * Nn; i += gsz) wsWf[i] = ldf(W, i, isbf);
    for (int i = gid; i < Nn; i += gsz) {
        wsb[i]     = ldf(bv, i, isbf);
        wsstart[i] = ldf(startt, i, isbf);
        wsend[i]   = ldf(endt, i, isbf);
        wsscm[i]   = ldb(sc, i, bw) ? 0.0f : NINF;
        wsecm[i]   = ldb(ec, i, bw) ? 0.0f : NINF;
    }
    for (int i = gid; i < Nn * Nn; i += gsz) {
        wstrans[i] = ldf(trans, i, isbf);
        wstc[i]    = ldb(tc, i, bw) ? 0.0f : NINF;
    }
}

// ---------------- lengths: one block per batch, shuffle-reduce ----------------
__global__ __launch_bounds__(256) void k_lengths(const void* mask, const int* flags,
                                                 int* lengths) {
    __shared__ int ws4[4];
    int r = blockIdx.x;
    int tid = threadIdx.x;
    int bw = flags[1];
    int s = (ldb(mask, r * Tn + tid, bw) ? 1 : 0)
          + (ldb(mask, r * Tn + 256 + tid, bw) ? 1 : 0);
    for (int off = 32; off; off >>= 1) s += __shfl_down(s, off, 64);
    if ((tid & 63) == 0) ws4[tid >> 6] = s;
    __syncthreads();
    if (tid == 0) lengths[r] = ws4[0] + ws4[1] + ws4[2] + ws4[3];
}

// ---------------- logits: strict np.einsum replication ----------------
// 2 threads per row: half0 owns j=0..11, half1 owns j=12..24. Per-j accumulation is
// sequential f32 (mul, add) over h = 0..767 ascending, NO fma — bit-identical to the
// reference einsum association.
__global__ __launch_bounds__(256) void k_gemm(
    const void* embv, const float* wsWf, const float* wsb,
    const int* flags, float* logitsF)
{
    __shared__ float etile[128][65];   // 128 rows x 64-h chunk, padded (odd stride)
    __shared__ float wtile[64][32];    // 64-h chunk x 25 cols, padded to 32 for float4
    __shared__ float s_b[25];

    int tid  = threadIdx.x;            // 0..255
    int r    = tid >> 1;               // row within block: 0..127
    int half = tid & 1;
    int j0   = half ? 12 : 0;          // half0: j 0..11, half1: j 12..24
    int row0 = blockIdx.x * 128;
    int row  = row0 + r;
    bool isbf = flags[0] != 0;

    if (tid < 25) s_b[tid] = wsb[tid];

    float acc[13];
#pragma unroll
    for (int k = 0; k < 13; k++) acc[k] = 0.0f;

    for (int c = 0; c < 12; c++) {
        __syncthreads();
        if (isbf) {
            const uint16_t* ep = (const uint16_t*)embv;
#pragma unroll
            for (int it = 0; it < 8; it++) {
                int idx = it * 256 + tid;        // 0..2047
                int rr = idx >> 4;
                int q  = idx & 15;
                const ushort4* p4 = (const ushort4*)(ep + (size_t)(row0 + rr) * Hn + c * 64);
                ushort4 u = p4[q];
                etile[rr][q * 4 + 0] = __bfloat162float(*(const __hip_bfloat16*)&u.x);
                etile[rr][q * 4 + 1] = __bfloat162float(*(const __hip_bfloat16*)&u.y);
                etile[rr][q * 4 + 2] = __bfloat162float(*(const __hip_bfloat16*)&u.z);
                etile[rr][q * 4 + 3] = __bfloat162float(*(const __hip_bfloat16*)&u.w);
            }
        } else {
            const float* ep = (const float*)embv;
#pragma unroll
            for (int it = 0; it < 8; it++) {
                int idx = it * 256 + tid;
                int rr = idx >> 4;
                int q  = idx & 15;
                const float4* p4 = (const float4*)(ep + (size_t)(row0 + rr) * Hn + c * 64);
                float4 v = p4[q];
                etile[rr][q * 4 + 0] = v.x;
                etile[rr][q * 4 + 1] = v.y;
                etile[rr][q * 4 + 2] = v.z;
                etile[rr][q * 4 + 3] = v.w;
            }
        }
        for (int i = tid; i < 1600; i += 256) {
            int hh = i / 25, j = i - hh * 25;
            wtile[hh][j] = wsWf[(size_t)(c * 64 + hh) * 25 + j];
        }
        __syncthreads();
        {
#pragma clang fp contract(off)
#pragma unroll 4
            for (int hh = 0; hh < 64; hh++) {
                float e = etile[r][hh];
                const float4* wp = (const float4*)&wtile[hh][j0];
                float4 w0 = wp[0];
                float4 w1 = wp[1];
                float4 w2 = wp[2];
                float  wl = wtile[hh][j0 + 12];
                acc[0]  = acc[0]  + e * w0.x;
                acc[1]  = acc[1]  + e * w0.y;
                acc[2]  = acc[2]  + e * w0.z;
                acc[3]  = acc[3]  + e * w0.w;
                acc[4]  = acc[4]  + e * w1.x;
                acc[5]  = acc[5]  + e * w1.y;
                acc[6]  = acc[6]  + e * w1.z;
                acc[7]  = acc[7]  + e * w1.w;
                acc[8]  = acc[8]  + e * w2.x;
                acc[9]  = acc[9]  + e * w2.y;
                acc[10] = acc[10] + e * w2.z;
                acc[11] = acc[11] + e * w2.w;
                acc[12] = acc[12] + e * wl;
            }
        }
    }

    int nj = half ? 13 : 12;
    {
#pragma clang fp contract(off)
        for (int k = 0; k < nj; k++) {
            int j = j0 + k;
            float lg = acc[k] + s_b[j];
            logitsF[(size_t)row * 25 + j] = lg;
        }
    }
}

// ---------------- lp expansion: fully parallel epilogue ----------------
__global__ __launch_bounds__(256) void k_lp(
    const float* logitsF, const float* wstrans, const float* wsstart, const float* wsend,
    const int* lengths, const int* flags, void* out)
{
    __shared__ float s_trans[625];
    __shared__ float s_start[25], s_end[25];
    int tid = threadIdx.x;
    for (int i = tid; i < 625; i += 256) s_trans[i] = wstrans[i];
    if (tid < 25) { s_start[tid] = wsstart[tid]; s_end[tid] = wsend[tid]; }
    __syncthreads();

    bool isbf = flags[0] != 0;
    int rw0 = blockIdx.x * 16;           // 2048 blocks; 16 (b,t) rows each, same batch
    int b = rw0 >> 9;
    int last = lengths[b] - 1;
    const float* lg0 = logitsF + (size_t)rw0 * 25;
    size_t obase = (size_t)rw0 * 625;

    for (int idx = tid; idx < 16 * 625; idx += 256) {
        int rr = idx / 625;
        int e  = idx - rr * 625;
        int i  = e / 25;
        int j  = e - i * 25;
        int t  = (rw0 + rr) & 511;
        float lg = lg0[rr * 25 + j];
        float v;
        {
#pragma clang fp contract(off)
            if (t == 0) v = s_start[j] + lg;
            else        v = lg + s_trans[e];
            if (t == last) v += s_end[j];
        }
        size_t o = obase + idx;
        if (isbf) ((__hip_bfloat16*)out)[o] = __float2bfloat16(v);
        else      ((float*)out)[o] = v;
    }
}

__device__ inline float rdlane(float v, int lane) {
    return __int_as_float(__builtin_amdgcn_readlane(__float_as_int(v), lane));
}
__device__ inline int imin2(int a, int b) { return a < b ? a : b; }

// ---------------- Viterbi: 1 wave per batch, exact f32 replication ----------------
// Each lane j computes ALL 25 candidates per step. Alphas are broadcast to SGPRs via
// v_readlane (no DS round-trip). Max is an fmaxf tree (max is associative — exact);
// index is first-k with s[k]==m (exact jnp.argmax first-occurrence). The time loop
// runs only t=1..last: in the t>=len frozen region the reference argmax provably
// self-loops on the running-argmax state, so tags[k>=last] == last_tag exactly.
// Backtrack prefetches bp rows (addresses known in advance) and chains only through
// dynamic-lane v_readlane.
__global__ __launch_bounds__(64) void k_viterbi(
    const float* logitsF, const float* wstrans, const float* wstc,
    const float* wsstart, const float* wsend, const float* wsscm, const float* wsecm,
    const int* lengths, const int* flags, void* out)
{
    __shared__ float   lgl[Tn * Nn];   // 51200 B: this batch's logits
    __shared__ uint8_t bp[511][32];    // 16352 B
    __shared__ uint8_t tags[512];

    int b  = blockIdx.x;
    int L  = threadIdx.x;
    bool act = (L < 25);
    int j  = act ? L : 0;
    int len  = lengths[b];
    int last = len - 1;
    bool isbf = flags[0] != 0;
    int padv = flags[2];

    // stage this batch's logits into LDS (coalesced float4)
    {
        const float4* src = (const float4*)(logitsF + (size_t)b * (Tn * Nn));
        float4* dst = (float4*)lgl;
        for (int i = L; i < (Tn * Nn) / 4; i += 64) dst[i] = src[i];
    }

    // loop-invariant per-lane columns (i = 0..24 -> candidate old-state)
    float tcol[25], tccol[25], ttc[25];
#pragma unroll
    for (int k = 0; k < 25; k++) {
        tcol[k]  = wstrans[k * 25 + j];
        tccol[k] = wstc[k * 25 + j];
        // ttc pre-add is exact when tc==0 (the only candidates that can win a
        // followed argmax; tc|eye guarantees the self-loop so NINF-class
        // candidates lose by >=9e4 — reassociation unobservable).
        ttc[k] = tcol[k] + tccol[k];
    }
    float endj = wsend[j];
    float ecmj = wsecm[j];

    __syncthreads();   // lgl ready

    // alpha0[j] = (start[j] + logits[b,0,j]) + scm[j]
    float areg;
    {
#pragma clang fp contract(off)
        areg = (wsstart[j] + lgl[j]) + wsscm[j];
    }

    float Lg0 = lgl[1 * 25 + j];
    float Lg1 = lgl[imin2(2, last) * 25 + j];

    for (int t = 1; t <= last; ++t) {
        int tp = imin2(t + 2, last);
        float Lgn = lgl[tp * 25 + j];          // distance-2 LDS prefetch

        float s[25];
        if (t < last) {
#pragma clang fp contract(off)
#pragma unroll
            for (int k = 0; k < 25; k++) {
                float ak = rdlane(areg, k);    // SGPR broadcast
                s[k] = ak + (Lg0 + ttc[k]);
            }
        } else {
#pragma clang fp contract(off)
#pragma unroll
            for (int k = 0; k < 25; k++) {
                float ak = rdlane(areg, k);
                float v = (((Lg0 + tcol[k]) + endj) + tccol[k]) + ecmj;
                s[k] = ak + v;
            }
        }

        // exact max: fmaxf tree (associative, no rounding)
        float a0 = fmaxf(fmaxf(s[0],  s[1]),  s[2]);
        float a1 = fmaxf(fmaxf(s[3],  s[4]),  s[5]);
        float a2 = fmaxf(fmaxf(s[6],  s[7]),  s[8]);
        float a3 = fmaxf(fmaxf(s[9],  s[10]), s[11]);
        float a4 = fmaxf(fmaxf(s[12], s[13]), s[14]);
        float a5 = fmaxf(fmaxf(s[15], s[16]), s[17]);
        float a6 = fmaxf(fmaxf(s[18], s[19]), s[20]);
        float a7 = fmaxf(fmaxf(s[21], s[22]), s[23]);
        float b0 = fmaxf(fmaxf(a0, a1), a2);
        float b1 = fmaxf(fmaxf(a3, a4), a5);
        float b2 = fmaxf(fmaxf(a6, a7), s[24]);
        float m  = fmaxf(fmaxf(b0, b1), b2);

        // first index with s[k]==m  (== jnp.argmax first-occurrence)
        int ik[25];
#pragma unroll
        for (int k = 0; k < 25; k++) ik[k] = (s[k] == m) ? k : 32;
        int q0 = imin2(imin2(ik[0],  ik[1]),  ik[2]);
        int q1 = imin2(imin2(ik[3],  ik[4]),  ik[5]);
        int q2 = imin2(imin2(ik[6],  ik[7]),  ik[8]);
        int q3 = imin2(imin2(ik[9],  ik[10]), ik[11]);
        int q4 = imin2(imin2(ik[12], ik[13]), ik[14]);
        int q5 = imin2(imin2(ik[15], ik[16]), ik[17]);
        int q6 = imin2(imin2(ik[18], ik[19]), ik[20]);
        int q7 = imin2(imin2(ik[21], ik[22]), ik[23]);
        int r0 = imin2(imin2(q0, q1), q2);
        int r1 = imin2(imin2(q3, q4), q5);
        int r2 = imin2(imin2(q6, q7), ik[24]);
        int mi = imin2(imin2(r0, r1), r2);

        areg = m;
        if (act) bp[t - 1][L] = (uint8_t)mi;
        Lg0 = Lg1; Lg1 = Lgn;
    }

    // wave-uniform argmax over final alpha (readlane chain, first-max)
    float am = rdlane(areg, 0);
    int ami = 0;
#pragma unroll
    for (int k = 1; k < 25; k++) {
        float v2 = rdlane(areg, k);
        bool g = v2 > am;
        am  = g ? v2 : am;
        ami = g ? k  : ami;
    }
    int tag = ami;
    if (L == 0) tags[last] = (uint8_t)tag;

    // backtrack: prefetch 8 bp rows per chunk (vector, independent), then chain
    // only through dynamic-lane readlane (~15cy/step instead of ~120cy DS latency).
    int Lc = L & 31;
    int k2 = last - 1;
    while (k2 >= 7) {
        int c0 = bp[k2    ][Lc];
        int c1 = bp[k2 - 1][Lc];
        int c2 = bp[k2 - 2][Lc];
        int c3 = bp[k2 - 3][Lc];
        int c4 = bp[k2 - 4][Lc];
        int c5 = bp[k2 - 5][Lc];
        int c6 = bp[k2 - 6][Lc];
        int c7 = bp[k2 - 7][Lc];
        tag = __builtin_amdgcn_readlane(c0, tag); if (L == 0) tags[k2    ] = (uint8_t)tag;
        tag = __builtin_amdgcn_readlane(c1, tag); if (L == 0) tags[k2 - 1] = (uint8_t)tag;
        tag = __builtin_amdgcn_readlane(c2, tag); if (L == 0) tags[k2 - 2] = (uint8_t)tag;
        tag = __builtin_amdgcn_readlane(c3, tag); if (L == 0) tags[k2 - 3] = (uint8_t)tag;
        tag = __builtin_amdgcn_readlane(c4, tag); if (L == 0) tags[k2 - 4] = (uint8_t)tag;
        tag = __builtin_amdgcn_readlane(c5, tag); if (L == 0) tags[k2 - 5] = (uint8_t)tag;
        tag = __builtin_amdgcn_readlane(c6, tag); if (L == 0) tags[k2 - 6] = (uint8_t)tag;
        tag = __builtin_amdgcn_readlane(c7, tag); if (L == 0) tags[k2 - 7] = (uint8_t)tag;
        k2 -= 8;
    }
    while (k2 >= 0) {
        int c = bp[k2][Lc];
        tag = __builtin_amdgcn_readlane(c, tag);
        if (L == 0) tags[k2] = (uint8_t)tag;
        k2--;
    }
    __syncthreads();

    size_t base = 20480000ull;  // B*T*N*N
    for (int t = L; t < 512; t += 64) {
        float val = (t < len) ? (float)tags[t] : (float)padv;
        size_t o = base + (size_t)b * 512 + t;
        if (isbf) ((__hip_bfloat16*)out)[o] = __float2bfloat16(val);
        else      ((float*)out)[o] = val;
    }
}

extern "C" void kernel_launch(void* const* d_in, const int* in_sizes, int n_in,
                              void* d_out, int out_size, void* d_ws, size_t ws_size,
                              hipStream_t stream) {
    const void* emb  = d_in[0];
    const void* W    = d_in[1];
    const void* bv   = d_in[2];
    const void* tr   = d_in[3];
    const void* st   = d_in[4];
    const void* en   = d_in[5];
    const void* mask = d_in[6];
    const void* sc   = d_in[7];
    const void* ec   = d_in[8];
    const void* tc   = d_in[9];
    const void* pad  = d_in[10];

    char* ws = (char*)d_ws;
    int*    flags    = (int*)ws;             // 64 B
    int*    lengths  = (int*)(ws + 64);      // 256 B
    float*  wsb      = (float*)(ws + 384);
    float*  wsstart  = (float*)(ws + 512);
    float*  wsend    = (float*)(ws + 640);
    float*  wsscm    = (float*)(ws + 768);
    float*  wsecm    = (float*)(ws + 896);
    float*  wstrans  = (float*)(ws + 1024);  // 2500 B
    float*  wstc     = (float*)(ws + 3584);  // 2500 B
    float*  wsWf     = (float*)(ws + 6144);  // 76800 B -> ends 82944
    float*  logitsF  = (float*)(ws + 82944); // 3276800 B -> ends ~3.36 MB

    k_detect<<<1, 64, 0, stream>>>(emb, mask, pad, flags);
    k_convert<<<64, 256, 0, stream>>>(W, bv, tr, st, en, sc, ec, tc, flags,
                                      wsWf, wsb, wsstart, wsend, wsscm, wsecm,
                                      wstrans, wstc);
    k_lengths<<<64, 256, 0, stream>>>(mask, flags, lengths);
    k_gemm<<<256, 256, 0, stream>>>(emb, wsWf, wsb, flags, logitsF);
    k_viterbi<<<64, 64, 0, stream>>>(logitsF, wstrans, wstc, wsstart, wsend,
                                     wsscm, wsecm, lengths, flags, d_out);
    k_lp<<<2048, 256, 0, stream>>>(logitsF, wstrans, wsstart, wsend,
                                   lengths, flags, d_out);
}

// Round 5
// 467.200 us; speedup vs baseline: 1.9554x; 1.0595x over previous
//
#include <hip/hip_runtime.h>
#include <hip/hip_bf16.h>
#include <stdint.h>

#define NINF -100000.0f

constexpr int Bn = 64, Tn = 512, Hn = 768, Nn = 25;

typedef float float2v __attribute__((ext_vector_type(2)));

__device__ inline float2v pk_mul(float2v a, float2v b) {
    float2v d;
    asm("v_pk_mul_f32 %0, %1, %2" : "=v"(d) : "v"(a), "v"(b));
    return d;
}
__device__ inline float2v pk_add(float2v a, float2v b) {
    float2v d;
    asm("v_pk_add_f32 %0, %1, %2" : "=v"(d) : "v"(a), "v"(b));
    return d;
}

__device__ inline float ldf(const void* p, int i, bool isbf) {
    if (isbf) return __bfloat162float(((const __hip_bfloat16*)p)[i]);
    return ((const float*)p)[i];
}
__device__ inline int ldb(const void* p, int i, int bw) {
    if (bw == 1) return (int)((const uint8_t*)p)[i];
    if (bw == 8) return ((const int*)p)[2 * i];
    return ((const int*)p)[i];
}

// ---------------- prep: detect + convert + lengths, one launch ----------------
// Each block derives isbf/bw LOCALLY (no cross-block dependency); block 0 also
// publishes flags for downstream kernels. Block b computes lengths[b]; conversion
// work is grid-strided across all 64 blocks.
__global__ __launch_bounds__(256) void k_prep(
    const void* emb, const void* mask, const void* padidx,
    const void* W, const void* bv, const void* trans, const void* startt, const void* endt,
    const void* sc, const void* ec, const void* tc,
    int* flags, float* wsWf,
    float* wsb, float* wsstart, float* wsend, float* wsscm, float* wsecm,
    float* wstrans, float* wstc, int* lengths)
{
    __shared__ int s_isbf, s_bw;
    __shared__ int ws4[4];
    int blk = blockIdx.x;
    int tid = threadIdx.x;

    if (tid < 64) {
        const uint16_t* e16 = (const uint16_t*)emb;
        uint16_t v = e16[tid];
        int ex = (v >> 7) & 0xFF;
        bool sane = (ex >= 100 && ex <= 140);
        unsigned long long ball = __ballot(sane);
        int cnt = __popcll(ball);
        if (tid == 0) {
            int isbf = (cnt >= 56) ? 1 : 0;
            const int* mw = (const int*)mask;
            int w0 = mw[0];
            int w1 = mw[1];
            int bw;
            if ((unsigned)w0 > 1u) bw = 1;
            else if (w0 == 1 && w1 == 0) bw = 8;
            else bw = 4;
            s_isbf = isbf; s_bw = bw;
            if (blk == 0) {
                flags[0] = isbf;
                flags[1] = bw;
                flags[2] = ((const int*)padidx)[0];
            }
        }
    }
    __syncthreads();
    bool isbf = s_isbf != 0;
    int bw = s_bw;

    // lengths for batch blk (256 threads, shuffle-reduce)
    {
        int s = (ldb(mask, blk * Tn + tid, bw) ? 1 : 0)
              + (ldb(mask, blk * Tn + 256 + tid, bw) ? 1 : 0);
        for (int off = 32; off; off >>= 1) s += __shfl_down(s, off, 64);
        if ((tid & 63) == 0) ws4[tid >> 6] = s;
        __syncthreads();
        if (tid == 0) lengths[blk] = ws4[0] + ws4[1] + ws4[2] + ws4[3];
    }

    // conversions, grid-strided
    int gid = blk * 256 + tid;
    int gsz = 64 * 256;
    for (int i = gid; i < Hn * Nn; i += gsz) wsWf[i] = ldf(W, i, isbf);
    for (int i = gid; i < Nn; i += gsz) {
        wsb[i]     = ldf(bv, i, isbf);
        wsstart[i] = ldf(startt, i, isbf);
        wsend[i]   = ldf(endt, i, isbf);
        wsscm[i]   = ldb(sc, i, bw) ? 0.0f : NINF;
        wsecm[i]   = ldb(ec, i, bw) ? 0.0f : NINF;
    }
    for (int i = gid; i < Nn * Nn; i += gsz) {
        wstrans[i] = ldf(trans, i, isbf);
        wstc[i]    = ldb(tc, i, bw) ? 0.0f : NINF;
    }
}

// ---------------- logits: strict np.einsum replication, packed f32 math ----------
// 2 threads per row: half0 owns j=0..11, half1 owns j=12..24. Per-j accumulation is
// sequential f32 (separate mul then add, NO fma) over h = 0..767 ascending —
// v_pk_mul_f32 / v_pk_add_f32 perform two independent IEEE f32 ops per instruction,
// so each j's arithmetic sequence is bit-identical to the reference C-einsum loop.
__global__ __launch_bounds__(256) void k_gemm(
    const void* embv, const float* wsWf, const float* wsb,
    const int* flags, float* logitsF)
{
    __shared__ float etile[128][65];   // 128 rows x 64-h chunk, padded (odd stride)
    __shared__ float wtile[64][32];    // 64-h chunk x 25 cols, padded to 32
    __shared__ float s_b[25];

    int tid  = threadIdx.x;            // 0..255
    int r    = tid >> 1;               // row within block: 0..127
    int half = tid & 1;
    int j0   = half ? 12 : 0;          // half0: j 0..11, half1: j 12..24
    int row0 = blockIdx.x * 128;
    int row  = row0 + r;
    bool isbf = flags[0] != 0;

    if (tid < 25) s_b[tid] = wsb[tid];

    float2v acc2[6];
#pragma unroll
    for (int k = 0; k < 6; k++) acc2[k] = (float2v){0.0f, 0.0f};
    float acc12 = 0.0f;                // half1: j24; half0: dummy (j12, unused)

    for (int c = 0; c < 12; c++) {
        __syncthreads();
        if (isbf) {
            const uint16_t* ep = (const uint16_t*)embv;
#pragma unroll
            for (int it = 0; it < 8; it++) {
                int idx = it * 256 + tid;        // 0..2047
                int rr = idx >> 4;
                int q  = idx & 15;
                const ushort4* p4 = (const ushort4*)(ep + (size_t)(row0 + rr) * Hn + c * 64);
                ushort4 u = p4[q];
                etile[rr][q * 4 + 0] = __bfloat162float(*(const __hip_bfloat16*)&u.x);
                etile[rr][q * 4 + 1] = __bfloat162float(*(const __hip_bfloat16*)&u.y);
                etile[rr][q * 4 + 2] = __bfloat162float(*(const __hip_bfloat16*)&u.z);
                etile[rr][q * 4 + 3] = __bfloat162float(*(const __hip_bfloat16*)&u.w);
            }
        } else {
            const float* ep = (const float*)embv;
#pragma unroll
            for (int it = 0; it < 8; it++) {
                int idx = it * 256 + tid;
                int rr = idx >> 4;
                int q  = idx & 15;
                const float4* p4 = (const float4*)(ep + (size_t)(row0 + rr) * Hn + c * 64);
                float4 v = p4[q];
                etile[rr][q * 4 + 0] = v.x;
                etile[rr][q * 4 + 1] = v.y;
                etile[rr][q * 4 + 2] = v.z;
                etile[rr][q * 4 + 3] = v.w;
            }
        }
        for (int i = tid; i < 1600; i += 256) {
            int hh = i / 25, j = i - hh * 25;
            wtile[hh][j] = wsWf[(size_t)(c * 64 + hh) * 25 + j];
        }
        __syncthreads();
        {
#pragma clang fp contract(off)
#pragma unroll 4
            for (int hh = 0; hh < 64; hh++) {
                float e = etile[r][hh];
                float2v ee = (float2v){e, e};
                const float4* wp = (const float4*)&wtile[hh][j0];
                float4 w0 = wp[0];
                float4 w1 = wp[1];
                float4 w2 = wp[2];
                float  wl = wtile[hh][j0 + 12];
                acc2[0] = pk_add(acc2[0], pk_mul(ee, (float2v){w0.x, w0.y}));
                acc2[1] = pk_add(acc2[1], pk_mul(ee, (float2v){w0.z, w0.w}));
                acc2[2] = pk_add(acc2[2], pk_mul(ee, (float2v){w1.x, w1.y}));
                acc2[3] = pk_add(acc2[3], pk_mul(ee, (float2v){w1.z, w1.w}));
                acc2[4] = pk_add(acc2[4], pk_mul(ee, (float2v){w2.x, w2.y}));
                acc2[5] = pk_add(acc2[5], pk_mul(ee, (float2v){w2.z, w2.w}));
                acc12 = acc12 + e * wl;
            }
        }
    }

    // logits = einsum + b  (one f32 add, ref association); halves write disjoint j
    {
#pragma clang fp contract(off)
#pragma unroll
        for (int p = 0; p < 6; p++) {
            int j = j0 + 2 * p;
            logitsF[(size_t)row * 25 + j]     = acc2[p][0] + s_b[j];
            logitsF[(size_t)row * 25 + j + 1] = acc2[p][1] + s_b[j + 1];
        }
        if (half) logitsF[(size_t)row * 25 + 24] = acc12 + s_b[24];
    }
}

__device__ inline float rdlane(float v, int lane) {
    return __int_as_float(__builtin_amdgcn_readlane(__float_as_int(v), lane));
}
__device__ inline int imin2(int a, int b) { return a < b ? a : b; }

// ---------------- tail: viterbi (blocks 0..63) + lp (blocks 64..2111), fused ------
// Both consume only logitsF + constants, so they run concurrently in one dispatch —
// the 2048 lp blocks keep the GPU busy (clock governor up) while the 64 serial
// viterbi recurrences run. Viterbi blocks: wave 0 runs the recurrence (barrier-free
// inner loop); all 4 waves help stage logits into LDS and write the tag output.
struct SharedV {
    float   lgl[Tn * Nn];    // 51200 B
    uint8_t bp[511][32];     // 16352 B
    uint8_t tags[512];
};
struct SharedL {
    float s_trans[625];
    float s_start[25];
    float s_end[25];
};

__global__ __launch_bounds__(256) void k_tail(
    const float* logitsF, const float* wstrans, const float* wstc,
    const float* wsstart, const float* wsend, const float* wsscm, const float* wsecm,
    const int* lengths, const int* flags, void* out)
{
    __shared__ union { SharedV v; SharedL l; } smem;
    int tid = threadIdx.x;
    bool isbf = flags[0] != 0;

    if (blockIdx.x >= 64) {
        // ---------------- lp expansion ----------------
        for (int i = tid; i < 625; i += 256) smem.l.s_trans[i] = wstrans[i];
        if (tid < 25) { smem.l.s_start[tid] = wsstart[tid]; smem.l.s_end[tid] = wsend[tid]; }
        __syncthreads();

        int rw0 = (blockIdx.x - 64) * 16;    // 16 (b,t) rows, same batch
        int b = rw0 >> 9;
        int last = lengths[b] - 1;
        const float* lg0 = logitsF + (size_t)rw0 * 25;
        size_t obase = (size_t)rw0 * 625;

        for (int idx = tid; idx < 16 * 625; idx += 256) {
            int rr = idx / 625;
            int e  = idx - rr * 625;
            int j  = e % 25;
            int t  = (rw0 + rr) & 511;
            float lg = lg0[rr * 25 + j];
            float v;
            {
#pragma clang fp contract(off)
                if (t == 0) v = smem.l.s_start[j] + lg;
                else        v = lg + smem.l.s_trans[e];
                if (t == last) v += smem.l.s_end[j];
            }
            size_t o = obase + idx;
            if (isbf) ((__hip_bfloat16*)out)[o] = __float2bfloat16(v);
            else      ((float*)out)[o] = v;
        }
        return;
    }

    // ---------------- viterbi ----------------
    int b  = blockIdx.x;
    int L  = tid;
    int len  = lengths[b];
    int last = len - 1;
    int padv = flags[2];

    // stage this batch's logits into LDS (coalesced float4, all 4 waves)
    {
        const float4* src = (const float4*)(logitsF + (size_t)b * (Tn * Nn));
        float4* dst = (float4*)smem.v.lgl;
        for (int i = tid; i < (Tn * Nn) / 4; i += 256) dst[i] = src[i];
    }
    __syncthreads();   // lgl ready

    if (L < 64) {
        bool act = (L < 25);
        int j = act ? L : 0;

        // loop-invariant per-lane columns (i = 0..24 -> candidate old-state)
        float tcol[25], tccol[25], ttc[25];
#pragma unroll
        for (int k = 0; k < 25; k++) {
            tcol[k]  = wstrans[k * 25 + j];
            tccol[k] = wstc[k * 25 + j];
            // ttc pre-add exact when tc==0 (only candidates that can win a followed
            // argmax; tc|eye guarantees the self-loop so NINF-class candidates lose
            // by >=9e4 — reassociation unobservable).
            ttc[k] = tcol[k] + tccol[k];
        }
        float endj = wsend[j];
        float ecmj = wsecm[j];

        // alpha0[j] = (start[j] + logits[b,0,j]) + scm[j]
        float areg;
        {
#pragma clang fp contract(off)
            areg = (wsstart[j] + smem.v.lgl[j]) + wsscm[j];
        }

        float Lg0 = smem.v.lgl[1 * 25 + j];
        float Lg1 = smem.v.lgl[imin2(2, last) * 25 + j];

        for (int t = 1; t <= last; ++t) {
            int tp = imin2(t + 2, last);
            float Lgn = smem.v.lgl[tp * 25 + j];   // distance-2 LDS prefetch

            float s[25];
            if (t < last) {
#pragma clang fp contract(off)
#pragma unroll
                for (int k = 0; k < 25; k++) {
                    float ak = rdlane(areg, k);    // SGPR broadcast
                    s[k] = ak + (Lg0 + ttc[k]);
                }
            } else {
#pragma clang fp contract(off)
#pragma unroll
                for (int k = 0; k < 25; k++) {
                    float ak = rdlane(areg, k);
                    float v = (((Lg0 + tcol[k]) + endj) + tccol[k]) + ecmj;
                    s[k] = ak + v;
                }
            }

            // exact max: fmaxf tree (associative, no rounding); maps to v_max3_f32
            float a0 = fmaxf(fmaxf(s[0],  s[1]),  s[2]);
            float a1 = fmaxf(fmaxf(s[3],  s[4]),  s[5]);
            float a2 = fmaxf(fmaxf(s[6],  s[7]),  s[8]);
            float a3 = fmaxf(fmaxf(s[9],  s[10]), s[11]);
            float a4 = fmaxf(fmaxf(s[12], s[13]), s[14]);
            float a5 = fmaxf(fmaxf(s[15], s[16]), s[17]);
            float a6 = fmaxf(fmaxf(s[18], s[19]), s[20]);
            float a7 = fmaxf(fmaxf(s[21], s[22]), s[23]);
            float b0 = fmaxf(fmaxf(a0, a1), a2);
            float b1 = fmaxf(fmaxf(a3, a4), a5);
            float b2 = fmaxf(fmaxf(a6, a7), s[24]);
            float m  = fmaxf(fmaxf(b0, b1), b2);

            // first index with s[k]==m  (== jnp.argmax first-occurrence)
            int ik[25];
#pragma unroll
            for (int k = 0; k < 25; k++) ik[k] = (s[k] == m) ? k : 32;
            int q0 = imin2(imin2(ik[0],  ik[1]),  ik[2]);
            int q1 = imin2(imin2(ik[3],  ik[4]),  ik[5]);
            int q2 = imin2(imin2(ik[6],  ik[7]),  ik[8]);
            int q3 = imin2(imin2(ik[9],  ik[10]), ik[11]);
            int q4 = imin2(imin2(ik[12], ik[13]), ik[14]);
            int q5 = imin2(imin2(ik[15], ik[16]), ik[17]);
            int q6 = imin2(imin2(ik[18], ik[19]), ik[20]);
            int q7 = imin2(imin2(ik[21], ik[22]), ik[23]);
            int r0 = imin2(imin2(q0, q1), q2);
            int r1 = imin2(imin2(q3, q4), q5);
            int r2 = imin2(imin2(q6, q7), ik[24]);
            int mi = imin2(imin2(r0, r1), r2);

            areg = m;
            if (act) smem.v.bp[t - 1][L] = (uint8_t)mi;
            Lg0 = Lg1; Lg1 = Lgn;
        }

        // wave-uniform argmax over final alpha (readlane chain, first-max)
        float am = rdlane(areg, 0);
        int ami = 0;
#pragma unroll
        for (int k = 1; k < 25; k++) {
            float v2 = rdlane(areg, k);
            bool g = v2 > am;
            am  = g ? v2 : am;
            ami = g ? k  : ami;
        }
        int tag = ami;
        if (L == 0) smem.v.tags[last] = (uint8_t)tag;

        // backtrack: prefetch 8 bp rows per chunk (independent LDS reads), then
        // chain only through dynamic-lane readlane.
        int Lc = L & 31;
        int k2 = last - 1;
        while (k2 >= 7) {
            int c0 = smem.v.bp[k2    ][Lc];
            int c1 = smem.v.bp[k2 - 1][Lc];
            int c2 = smem.v.bp[k2 - 2][Lc];
            int c3 = smem.v.bp[k2 - 3][Lc];
            int c4 = smem.v.bp[k2 - 4][Lc];
            int c5 = smem.v.bp[k2 - 5][Lc];
            int c6 = smem.v.bp[k2 - 6][Lc];
            int c7 = smem.v.bp[k2 - 7][Lc];
            tag = __builtin_amdgcn_readlane(c0, tag); if (L == 0) smem.v.tags[k2    ] = (uint8_t)tag;
            tag = __builtin_amdgcn_readlane(c1, tag); if (L == 0) smem.v.tags[k2 - 1] = (uint8_t)tag;
            tag = __builtin_amdgcn_readlane(c2, tag); if (L == 0) smem.v.tags[k2 - 2] = (uint8_t)tag;
            tag = __builtin_amdgcn_readlane(c3, tag); if (L == 0) smem.v.tags[k2 - 3] = (uint8_t)tag;
            tag = __builtin_amdgcn_readlane(c4, tag); if (L == 0) smem.v.tags[k2 - 4] = (uint8_t)tag;
            tag = __builtin_amdgcn_readlane(c5, tag); if (L == 0) smem.v.tags[k2 - 5] = (uint8_t)tag;
            tag = __builtin_amdgcn_readlane(c6, tag); if (L == 0) smem.v.tags[k2 - 6] = (uint8_t)tag;
            tag = __builtin_amdgcn_readlane(c7, tag); if (L == 0) smem.v.tags[k2 - 7] = (uint8_t)tag;
            k2 -= 8;
        }
        while (k2 >= 0) {
            int c = smem.v.bp[k2][Lc];
            tag = __builtin_amdgcn_readlane(c, tag);
            if (L == 0) smem.v.tags[k2] = (uint8_t)tag;
            k2--;
        }
    }
    __syncthreads();

    size_t base = 20480000ull;  // B*T*N*N
    for (int t = tid; t < 512; t += 256) {
        float val = (t < len) ? (float)smem.v.tags[t] : (float)padv;
        size_t o = base + (size_t)b * 512 + t;
        if (isbf) ((__hip_bfloat16*)out)[o] = __float2bfloat16(val);
        else      ((float*)out)[o] = val;
    }
}

extern "C" void kernel_launch(void* const* d_in, const int* in_sizes, int n_in,
                              void* d_out, int out_size, void* d_ws, size_t ws_size,
                              hipStream_t stream) {
    const void* emb  = d_in[0];
    const void* W    = d_in[1];
    const void* bv   = d_in[2];
    const void* tr   = d_in[3];
    const void* st   = d_in[4];
    const void* en   = d_in[5];
    const void* mask = d_in[6];
    const void* sc   = d_in[7];
    const void* ec   = d_in[8];
    const void* tc   = d_in[9];
    const void* pad  = d_in[10];

    char* ws = (char*)d_ws;
    int*    flags    = (int*)ws;             // 64 B
    int*    lengths  = (int*)(ws + 64);      // 256 B
    float*  wsb      = (float*)(ws + 384);
    float*  wsstart  = (float*)(ws + 512);
    float*  wsend    = (float*)(ws + 640);
    float*  wsscm    = (float*)(ws + 768);
    float*  wsecm    = (float*)(ws + 896);
    float*  wstrans  = (float*)(ws + 1024);  // 2500 B
    float*  wstc     = (float*)(ws + 3584);  // 2500 B
    float*  wsWf     = (float*)(ws + 6144);  // 76800 B -> ends 82944
    float*  logitsF  = (float*)(ws + 82944); // 3276800 B -> ends ~3.36 MB

    k_prep<<<64, 256, 0, stream>>>(emb, mask, pad, W, bv, tr, st, en, sc, ec, tc,
                                   flags, wsWf, wsb, wsstart, wsend, wsscm, wsecm,
                                   wstrans, wstc, lengths);
    k_gemm<<<256, 256, 0, stream>>>(emb, wsWf, wsb, flags, logitsF);
    k_tail<<<2112, 256, 0, stream>>>(logitsF, wstrans, wstc, wsstart, wsend,
                                     wsscm, wsecm, lengths, flags, d_out);
}

// Round 6
// 415.036 us; speedup vs baseline: 2.2012x; 1.1257x over previous
//
#include <hip/hip_runtime.h>
#include <hip/hip_bf16.h>
#include <stdint.h>

#define NINF -100000.0f

constexpr int Bn = 64, Tn = 512, Hn = 768, Nn = 25;

typedef float float2v __attribute__((ext_vector_type(2)));

__device__ inline float2v pk_mul(float2v a, float2v b) {
    float2v d;
    asm("v_pk_mul_f32 %0, %1, %2" : "=v"(d) : "v"(a), "v"(b));
    return d;
}
__device__ inline float2v pk_add(float2v a, float2v b) {
    float2v d;
    asm("v_pk_add_f32 %0, %1, %2" : "=v"(d) : "v"(a), "v"(b));
    return d;
}

__device__ inline float ldf(const void* p, int i, bool isbf) {
    if (isbf) return __bfloat162float(((const __hip_bfloat16*)p)[i]);
    return ((const float*)p)[i];
}
__device__ inline int ldb(const void* p, int i, int bw) {
    if (bw == 1) return (int)((const uint8_t*)p)[i];
    if (bw == 8) return ((const int*)p)[2 * i];
    return ((const int*)p)[i];
}

// ---------------- prep: detect + convert + lengths, one launch ----------------
__global__ __launch_bounds__(256) void k_prep(
    const void* emb, const void* mask, const void* padidx,
    const void* W, const void* bv, const void* trans, const void* startt, const void* endt,
    const void* sc, const void* ec, const void* tc,
    int* flags, float* wsWf,
    float* wsb, float* wsstart, float* wsend, float* wsscm, float* wsecm,
    float* wstrans, float* wstc, int* lengths)
{
    __shared__ int s_isbf, s_bw;
    __shared__ int ws4[4];
    int blk = blockIdx.x;
    int tid = threadIdx.x;

    if (tid < 64) {
        const uint16_t* e16 = (const uint16_t*)emb;
        uint16_t v = e16[tid];
        int ex = (v >> 7) & 0xFF;
        bool sane = (ex >= 100 && ex <= 140);
        unsigned long long ball = __ballot(sane);
        int cnt = __popcll(ball);
        if (tid == 0) {
            int isbf = (cnt >= 56) ? 1 : 0;
            const int* mw = (const int*)mask;
            int w0 = mw[0];
            int w1 = mw[1];
            int bw;
            if ((unsigned)w0 > 1u) bw = 1;
            else if (w0 == 1 && w1 == 0) bw = 8;
            else bw = 4;
            s_isbf = isbf; s_bw = bw;
            if (blk == 0) {
                flags[0] = isbf;
                flags[1] = bw;
                flags[2] = ((const int*)padidx)[0];
            }
        }
    }
    __syncthreads();
    bool isbf = s_isbf != 0;
    int bw = s_bw;

    {
        int s = (ldb(mask, blk * Tn + tid, bw) ? 1 : 0)
              + (ldb(mask, blk * Tn + 256 + tid, bw) ? 1 : 0);
        for (int off = 32; off; off >>= 1) s += __shfl_down(s, off, 64);
        if ((tid & 63) == 0) ws4[tid >> 6] = s;
        __syncthreads();
        if (tid == 0) lengths[blk] = ws4[0] + ws4[1] + ws4[2] + ws4[3];
    }

    int gid = blk * 256 + tid;
    int gsz = 64 * 256;
    for (int i = gid; i < Hn * Nn; i += gsz) wsWf[i] = ldf(W, i, isbf);
    for (int i = gid; i < Nn; i += gsz) {
        wsb[i]     = ldf(bv, i, isbf);
        wsstart[i] = ldf(startt, i, isbf);
        wsend[i]   = ldf(endt, i, isbf);
        wsscm[i]   = ldb(sc, i, bw) ? 0.0f : NINF;
        wsecm[i]   = ldb(ec, i, bw) ? 0.0f : NINF;
    }
    for (int i = gid; i < Nn * Nn; i += gsz) {
        wstrans[i] = ldf(trans, i, isbf);
        wstc[i]    = ldb(tc, i, bw) ? 0.0f : NINF;
    }
}

// ---------------- logits: strict np.einsum replication, packed f32 math ----------
// 512 blocks x 128 threads (2 blocks/CU for block-level latency overlap).
// 2 threads per row: half0 owns j=0..11, half1 owns j=12..24. Per-j accumulation is
// sequential f32 (separate mul then add, NO fma) over h = 0..767 ascending —
// v_pk_mul_f32 / v_pk_add_f32 do two independent IEEE f32 ops per instruction, so
// each j's arithmetic sequence is bit-identical to the reference C-einsum loop.
__global__ __launch_bounds__(128) void k_gemm(
    const void* embv, const float* wsWf, const float* wsb,
    const int* flags, float* logitsF)
{
    __shared__ float etile[64][65];    // 64 rows x 64-h chunk, padded (odd stride)
    __shared__ float wtile[64][32];    // 64-h chunk x 25 cols, padded to 32
    __shared__ float s_b[25];

    int tid  = threadIdx.x;            // 0..127
    int r    = tid >> 1;               // row within block: 0..63
    int half = tid & 1;
    int j0   = half ? 12 : 0;          // half0: j 0..11, half1: j 12..24
    int row0 = blockIdx.x * 64;
    int row  = row0 + r;
    bool isbf = flags[0] != 0;

    if (tid < 25) s_b[tid] = wsb[tid];

    float2v acc2[6];
#pragma unroll
    for (int k = 0; k < 6; k++) acc2[k] = (float2v){0.0f, 0.0f};
    float acc12 = 0.0f;                // half1: j24; half0: dummy (j12, unused)

    for (int c = 0; c < 12; c++) {
        __syncthreads();
        if (isbf) {
            const uint16_t* ep = (const uint16_t*)embv;
#pragma unroll
            for (int it = 0; it < 8; it++) {
                int idx = it * 128 + tid;        // 0..1023
                int rr = idx >> 4;
                int q  = idx & 15;
                const ushort4* p4 = (const ushort4*)(ep + (size_t)(row0 + rr) * Hn + c * 64);
                ushort4 u = p4[q];
                etile[rr][q * 4 + 0] = __bfloat162float(*(const __hip_bfloat16*)&u.x);
                etile[rr][q * 4 + 1] = __bfloat162float(*(const __hip_bfloat16*)&u.y);
                etile[rr][q * 4 + 2] = __bfloat162float(*(const __hip_bfloat16*)&u.z);
                etile[rr][q * 4 + 3] = __bfloat162float(*(const __hip_bfloat16*)&u.w);
            }
        } else {
            const float* ep = (const float*)embv;
#pragma unroll
            for (int it = 0; it < 8; it++) {
                int idx = it * 128 + tid;
                int rr = idx >> 4;
                int q  = idx & 15;
                const float4* p4 = (const float4*)(ep + (size_t)(row0 + rr) * Hn + c * 64);
                float4 v = p4[q];
                etile[rr][q * 4 + 0] = v.x;
                etile[rr][q * 4 + 1] = v.y;
                etile[rr][q * 4 + 2] = v.z;
                etile[rr][q * 4 + 3] = v.w;
            }
        }
        for (int i = tid; i < 1600; i += 128) {
            int hh = i / 25, j = i - hh * 25;
            wtile[hh][j] = wsWf[(size_t)(c * 64 + hh) * 25 + j];
        }
        __syncthreads();
        {
#pragma clang fp contract(off)
#pragma unroll 4
            for (int hh = 0; hh < 64; hh++) {
                float e = etile[r][hh];
                float2v ee = (float2v){e, e};
                const float4* wp = (const float4*)&wtile[hh][j0];
                float4 w0 = wp[0];
                float4 w1 = wp[1];
                float4 w2 = wp[2];
                float  wl = wtile[hh][j0 + 12];
                acc2[0] = pk_add(acc2[0], pk_mul(ee, (float2v){w0.x, w0.y}));
                acc2[1] = pk_add(acc2[1], pk_mul(ee, (float2v){w0.z, w0.w}));
                acc2[2] = pk_add(acc2[2], pk_mul(ee, (float2v){w1.x, w1.y}));
                acc2[3] = pk_add(acc2[3], pk_mul(ee, (float2v){w1.z, w1.w}));
                acc2[4] = pk_add(acc2[4], pk_mul(ee, (float2v){w2.x, w2.y}));
                acc2[5] = pk_add(acc2[5], pk_mul(ee, (float2v){w2.z, w2.w}));
                acc12 = acc12 + e * wl;
            }
        }
    }

    {
#pragma clang fp contract(off)
#pragma unroll
        for (int p = 0; p < 6; p++) {
            int j = j0 + 2 * p;
            logitsF[(size_t)row * 25 + j]     = acc2[p][0] + s_b[j];
            logitsF[(size_t)row * 25 + j + 1] = acc2[p][1] + s_b[j + 1];
        }
        if (half) logitsF[(size_t)row * 25 + 24] = acc12 + s_b[24];
    }
}

__device__ inline float rdlane(float v, int lane) {
    return __int_as_float(__builtin_amdgcn_readlane(__float_as_int(v), lane));
}
__device__ inline int imin2(int a, int b) { return a < b ? a : b; }

// ---------------- tail: viterbi (blocks 0..63) + lp (blocks 64..2111), fused ------
// Viterbi restructured into phases:
//   A (wave 0): max-only recurrence, alpha rows (f32) stored to LDS. The argmax
//     index scan is NOT loop-carried, so it is removed from the serial wave.
//   B (all 8 waves): recompute s[k] bit-identically from stored alpha rows (same
//     operands, same fp-contract-off ordering -> bit-equal), equality-scan vs the
//     stored row max, min-tree -> bp[t][j]. 8-way parallel over t.
//   Trace (wave 0): readlane-chain backtrack (unchanged).
// lp blocks are unchanged and absorbed under phase A's shadow.
struct SharedV {
    float   lgl[Tn * Nn];    // 51200 B
    float   alpha[Tn][26];   // 53248 B
    uint8_t bp[511][32];     // 16352 B
    uint8_t tags[512];
};
struct SharedL {
    float s_trans[625];
    float s_start[25];
    float s_end[25];
};

__global__ __launch_bounds__(512) void k_tail(
    const float* logitsF, const float* wstrans, const float* wstc,
    const float* wsstart, const float* wsend, const float* wsscm, const float* wsecm,
    const int* lengths, const int* flags, void* out)
{
    __shared__ union { SharedV v; SharedL l; } smem;
    int tid = threadIdx.x;
    bool isbf = flags[0] != 0;

    if (blockIdx.x >= 64) {
        // ---------------- lp expansion ----------------
        for (int i = tid; i < 625; i += 512) smem.l.s_trans[i] = wstrans[i];
        if (tid < 25) { smem.l.s_start[tid] = wsstart[tid]; smem.l.s_end[tid] = wsend[tid]; }
        __syncthreads();

        int rw0 = (blockIdx.x - 64) * 16;    // 16 (b,t) rows, same batch
        int b = rw0 >> 9;
        int last = lengths[b] - 1;
        const float* lg0 = logitsF + (size_t)rw0 * 25;
        size_t obase = (size_t)rw0 * 625;

        for (int idx = tid; idx < 16 * 625; idx += 512) {
            int rr = idx / 625;
            int e  = idx - rr * 625;
            int j  = e % 25;
            int t  = (rw0 + rr) & 511;
            float lg = lg0[rr * 25 + j];
            float v;
            {
#pragma clang fp contract(off)
                if (t == 0) v = smem.l.s_start[j] + lg;
                else        v = lg + smem.l.s_trans[e];
                if (t == last) v += smem.l.s_end[j];
            }
            size_t o = obase + idx;
            if (isbf) ((__hip_bfloat16*)out)[o] = __float2bfloat16(v);
            else      ((float*)out)[o] = v;
        }
        return;
    }

    // ---------------- viterbi ----------------
    int b  = blockIdx.x;
    int len  = lengths[b];
    int last = len - 1;
    int padv = flags[2];
    int L   = tid & 63;
    int wid = tid >> 6;
    bool act = (L < 25);
    int j = act ? L : 0;

    // stage this batch's logits into LDS (coalesced float4, all 8 waves)
    {
        const float4* src = (const float4*)(logitsF + (size_t)b * (Tn * Nn));
        float4* dst = (float4*)smem.v.lgl;
        for (int i = tid; i < (Tn * Nn) / 4; i += 512) dst[i] = src[i];
    }

    // loop-invariant per-lane columns — loaded by ALL waves (phase B needs them).
    float tcol[25], tccol[25], ttc[25];
#pragma unroll
    for (int k = 0; k < 25; k++) {
        tcol[k]  = wstrans[k * 25 + j];
        tccol[k] = wstc[k * 25 + j];
        // ttc pre-add exact when tc==0 (only candidates that can win a followed
        // argmax; tc|eye guarantees the self-loop so NINF-class candidates lose
        // by >=9e4 — reassociation unobservable).
        ttc[k] = tcol[k] + tccol[k];
    }
    float endj = wsend[j];
    float ecmj = wsecm[j];

    __syncthreads();   // lgl ready

    float areg = 0.0f;   // final alpha (valid in wave 0 lanes 0..24 after phase A)
    if (wid == 0) {
        // ---- phase A: max-only forward, alpha rows to LDS ----
        {
#pragma clang fp contract(off)
            areg = (wsstart[j] + smem.v.lgl[j]) + wsscm[j];
        }
        if (act) smem.v.alpha[0][L] = areg;

        float Lg0 = smem.v.lgl[25 + j];
        float Lg1 = smem.v.lgl[imin2(2, last) * 25 + j];

        for (int t = 1; t <= last; ++t) {
            float Lgn = smem.v.lgl[imin2(t + 2, last) * 25 + j];

            float s[25];
            if (t < last) {
#pragma clang fp contract(off)
#pragma unroll
                for (int k = 0; k < 25; k++) {
                    float ak = rdlane(areg, k);
                    s[k] = ak + (Lg0 + ttc[k]);
                }
            } else {
#pragma clang fp contract(off)
#pragma unroll
                for (int k = 0; k < 25; k++) {
                    float ak = rdlane(areg, k);
                    float v = (((Lg0 + tcol[k]) + endj) + tccol[k]) + ecmj;
                    s[k] = ak + v;
                }
            }

            // exact max: fmaxf tree (associative, no rounding); max3-friendly shape
            float a0 = fmaxf(fmaxf(s[0],  s[1]),  s[2]);
            float a1 = fmaxf(fmaxf(s[3],  s[4]),  s[5]);
            float a2 = fmaxf(fmaxf(s[6],  s[7]),  s[8]);
            float a3 = fmaxf(fmaxf(s[9],  s[10]), s[11]);
            float a4 = fmaxf(fmaxf(s[12], s[13]), s[14]);
            float a5 = fmaxf(fmaxf(s[15], s[16]), s[17]);
            float a6 = fmaxf(fmaxf(s[18], s[19]), s[20]);
            float a7 = fmaxf(fmaxf(s[21], s[22]), s[23]);
            float b0 = fmaxf(fmaxf(a0, a1), a2);
            float b1 = fmaxf(fmaxf(a3, a4), a5);
            float b2 = fmaxf(fmaxf(a6, a7), s[24]);
            float m  = fmaxf(fmaxf(b0, b1), b2);

            areg = m;
            if (act) smem.v.alpha[t][L] = m;
            Lg0 = Lg1; Lg1 = Lgn;
        }
    }
    __syncthreads();   // alpha rows ready

    // ---- phase B: bp[t][j], 8-way parallel over t ----
    for (int t = 1 + wid; t <= last; t += 8) {
        float ap = smem.v.alpha[t - 1][j];   // lane L holds alpha[t-1][L]
        float mj = smem.v.alpha[t][j];       // this j's row max
        float Lg = smem.v.lgl[t * 25 + j];

        float s[25];
        if (t < last) {
#pragma clang fp contract(off)
#pragma unroll
            for (int k = 0; k < 25; k++) {
                float ak = rdlane(ap, k);
                s[k] = ak + (Lg + ttc[k]);
            }
        } else {
#pragma clang fp contract(off)
#pragma unroll
            for (int k = 0; k < 25; k++) {
                float ak = rdlane(ap, k);
                float v = (((Lg + tcol[k]) + endj) + tccol[k]) + ecmj;
                s[k] = ak + v;
            }
        }

        // first index with s[k]==mj  (== jnp.argmax first-occurrence; s recomputed
        // bit-identically to phase A, and the fmax-tree max is exact)
        int ik[25];
#pragma unroll
        for (int k = 0; k < 25; k++) ik[k] = (s[k] == mj) ? k : 32;
        int q0 = imin2(imin2(ik[0],  ik[1]),  ik[2]);
        int q1 = imin2(imin2(ik[3],  ik[4]),  ik[5]);
        int q2 = imin2(imin2(ik[6],  ik[7]),  ik[8]);
        int q3 = imin2(imin2(ik[9],  ik[10]), ik[11]);
        int q4 = imin2(imin2(ik[12], ik[13]), ik[14]);
        int q5 = imin2(imin2(ik[15], ik[16]), ik[17]);
        int q6 = imin2(imin2(ik[18], ik[19]), ik[20]);
        int q7 = imin2(imin2(ik[21], ik[22]), ik[23]);
        int r0 = imin2(imin2(q0, q1), q2);
        int r1 = imin2(imin2(q3, q4), q5);
        int r2 = imin2(imin2(q6, q7), ik[24]);
        int mi = imin2(imin2(r0, r1), r2);

        if (act) smem.v.bp[t - 1][L] = (uint8_t)mi;
    }
    __syncthreads();   // bp ready

    if (wid == 0) {
        // wave-uniform argmax over final alpha (readlane chain, first-max)
        float am = rdlane(areg, 0);
        int ami = 0;
#pragma unroll
        for (int k = 1; k < 25; k++) {
            float v2 = rdlane(areg, k);
            bool g = v2 > am;
            am  = g ? v2 : am;
            ami = g ? k  : ami;
        }
        int tag = ami;
        if (L == 0) smem.v.tags[last] = (uint8_t)tag;

        // backtrack: prefetch 8 bp rows per chunk (independent LDS reads), then
        // chain only through dynamic-lane readlane.
        int Lc = L & 31;
        int k2 = last - 1;
        while (k2 >= 7) {
            int c0 = smem.v.bp[k2    ][Lc];
            int c1 = smem.v.bp[k2 - 1][Lc];
            int c2 = smem.v.bp[k2 - 2][Lc];
            int c3 = smem.v.bp[k2 - 3][Lc];
            int c4 = smem.v.bp[k2 - 4][Lc];
            int c5 = smem.v.bp[k2 - 5][Lc];
            int c6 = smem.v.bp[k2 - 6][Lc];
            int c7 = smem.v.bp[k2 - 7][Lc];
            tag = __builtin_amdgcn_readlane(c0, tag); if (L == 0) smem.v.tags[k2    ] = (uint8_t)tag;
            tag = __builtin_amdgcn_readlane(c1, tag); if (L == 0) smem.v.tags[k2 - 1] = (uint8_t)tag;
            tag = __builtin_amdgcn_readlane(c2, tag); if (L == 0) smem.v.tags[k2 - 2] = (uint8_t)tag;
            tag = __builtin_amdgcn_readlane(c3, tag); if (L == 0) smem.v.tags[k2 - 3] = (uint8_t)tag;
            tag = __builtin_amdgcn_readlane(c4, tag); if (L == 0) smem.v.tags[k2 - 4] = (uint8_t)tag;
            tag = __builtin_amdgcn_readlane(c5, tag); if (L == 0) smem.v.tags[k2 - 5] = (uint8_t)tag;
            tag = __builtin_amdgcn_readlane(c6, tag); if (L == 0) smem.v.tags[k2 - 6] = (uint8_t)tag;
            tag = __builtin_amdgcn_readlane(c7, tag); if (L == 0) smem.v.tags[k2 - 7] = (uint8_t)tag;
            k2 -= 8;
        }
        while (k2 >= 0) {
            int c = smem.v.bp[k2][Lc];
            tag = __builtin_amdgcn_readlane(c, tag);
            if (L == 0) smem.v.tags[k2] = (uint8_t)tag;
            k2--;
        }
    }
    __syncthreads();

    size_t base = 20480000ull;  // B*T*N*N
    for (int t = tid; t < 512; t += 512) {
        float val = (t < len) ? (float)smem.v.tags[t] : (float)padv;
        size_t o = base + (size_t)b * 512 + t;
        if (isbf) ((__hip_bfloat16*)out)[o] = __float2bfloat16(val);
        else      ((float*)out)[o] = val;
    }
}

extern "C" void kernel_launch(void* const* d_in, const int* in_sizes, int n_in,
                              void* d_out, int out_size, void* d_ws, size_t ws_size,
                              hipStream_t stream) {
    const void* emb  = d_in[0];
    const void* W    = d_in[1];
    const void* bv   = d_in[2];
    const void* tr   = d_in[3];
    const void* st   = d_in[4];
    const void* en   = d_in[5];
    const void* mask = d_in[6];
    const void* sc   = d_in[7];
    const void* ec   = d_in[8];
    const void* tc   = d_in[9];
    const void* pad  = d_in[10];

    char* ws = (char*)d_ws;
    int*    flags    = (int*)ws;             // 64 B
    int*    lengths  = (int*)(ws + 64);      // 256 B
    float*  wsb      = (float*)(ws + 384);
    float*  wsstart  = (float*)(ws + 512);
    float*  wsend    = (float*)(ws + 640);
    float*  wsscm    = (float*)(ws + 768);
    float*  wsecm    = (float*)(ws + 896);
    float*  wstrans  = (float*)(ws + 1024);  // 2500 B
    float*  wstc     = (float*)(ws + 3584);  // 2500 B
    float*  wsWf     = (float*)(ws + 6144);  // 76800 B -> ends 82944
    float*  logitsF  = (float*)(ws + 82944); // 3276800 B -> ends ~3.36 MB

    k_prep<<<64, 256, 0, stream>>>(emb, mask, pad, W, bv, tr, st, en, sc, ec, tc,
                                   flags, wsWf, wsb, wsstart, wsend, wsscm, wsecm,
                                   wstrans, wstc, lengths);
    k_gemm<<<512, 128, 0, stream>>>(emb, wsWf, wsb, flags, logitsF);
    k_tail<<<2112, 512, 0, stream>>>(logitsF, wstrans, wstc, wsstart, wsend,
                                     wsscm, wsecm, lengths, flags, d_out);
}